// Round 8
// baseline (1622.117 us; speedup 1.0000x reference)
//
#include <hip/hip_runtime.h>
#include <math.h>

#define NSTATES 21
#define NPULSES 128
#define BATCH   8192
#define BPB     12   // batch elems per block: 4 waves x 3 per wave

typedef float v4f __attribute__((ext_vector_type(4)));

// ---------------- PROBE KERNELS (write d_ws; diagnostic only) ----------------
// Exact fill-replica structure: grid-stride monotonic sweep of dwordx4 stores.
// const: uniform value (0xAA pattern, same as harness poison fill).
// vary : per-address incompressible value, same instruction structure.
__global__ __launch_bounds__(256) void probe_fill_const(v4f* __restrict__ dst,
                                                        long n4, int sweeps) {
    const long stride = (long)gridDim.x * 256;
    const long t0 = (long)blockIdx.x * 256 + threadIdx.x;
    const float a = __uint_as_float(0xAAAAAAAAu);
    const v4f val = {a, a, a, a};
    for (int s = 0; s < sweeps; ++s)
        for (long i = t0; i < n4; i += stride)
            dst[i] = val;
}

__global__ __launch_bounds__(256) void probe_fill_vary(v4f* __restrict__ dst,
                                                       long n4, int sweeps) {
    const long stride = (long)gridDim.x * 256;
    const long t0 = (long)blockIdx.x * 256 + threadIdx.x;
    for (int s = 0; s < sweeps; ++s)
        for (long i = t0; i < n4; i += stride) {
            unsigned u = (unsigned)i * 2654435761u + (unsigned)s;
            v4f val = {__uint_as_float(u),
                       __uint_as_float(u ^ 0x5A5A5A5Au),
                       __uint_as_float(u + 0x9E3779B9u),
                       __uint_as_float(~u)};
            dst[i] = val;
        }
}

// ---------------- MAIN KERNEL: R2 verbatim (fastest, 205.9 us) ----------------
__global__ __launch_bounds__(256) void epg_mt_kernel(
    const float* __restrict__ fa_arr,
    const float* __restrict__ ph_arr,
    const float* __restrict__ T1f, const float* __restrict__ T2f,
    const float* __restrict__ T1b, const float* __restrict__ T2b,
    const float* __restrict__ kfp, const float* __restrict__ kbp,
    const float* __restrict__ B0p, const float* __restrict__ B1p,
    const float* __restrict__ wfp, const float* __restrict__ wbp,
    const int*   __restrict__ TRp,
    float* __restrict__ out)
{
    __shared__ float lds[2][BPB * NSTATES * 10];   // 2 x 2520 floats

    const int tid  = threadIdx.x;
    const int lane = tid & 63;
    const int g    = lane / 21;
    const int s    = lane - g * 21;
    const int lb   = (tid >> 6) * 3 + g;
    const int b0   = blockIdx.x * BPB;
    const int b    = b0 + lb;
    const bool valid = (g < 3) && (b < BATCH);
    const int bc   = valid ? b : 0;

    for (int i = tid; i < 2 * BPB * NSTATES * 10; i += 256)
        ((float*)lds)[i] = 0.f;

    const float tr  = (float)TRp[0];
    const float dt  = tr * 0.001f;
    const float E1f = expf(-tr / T1f[bc]);
    const float E2f = expf(-tr / T2f[bc]);
    const float E1b = expf(-tr / T1b[bc]);
    const float kfdt = kfp[bc] * dt;
    const float kbdt = kbp[bc] * dt;
    const float phi  = 6.28318530717958647692f * B0p[bc] * dt;
    const float b0c  = cosf(phi), b0s = sinf(phi);
    const float wfv  = wfp[bc], wbv = wbp[bc];
    const float add0f = (s == 0) ? (1.0f - E1f) * wfv : 0.0f;
    const float add0b = (s == 0) ? (1.0f - E1b) * wbv : 0.0f;
    const float b1   = B1p[bc];

    float Fpr = 0.f, Fpi = 0.f, Fmr = 0.f, Fmi = 0.f;
    float Zf = (s == 0) ? wfv : 0.f;
    float Zb = (s == 0) ? wbv : 0.f;

    const int nb = (BATCH - b0 < BPB) ? (BATCH - b0) : BPB;
    const int n4 = (nb * NSTATES * 10) >> 2;
    const size_t pstride = (size_t)BATCH * NSTATES * 10;
    float* outb = out + (size_t)b0 * (NSTATES * 10);

    __syncthreads();

    for (int p = 0; p < NPULSES; ++p) {
        const float fa = fa_arr[p];
        const float ph = ph_arr[p];

        Fpr *= E2f; Fpi *= E2f; Fmr *= E2f; Fmi *= E2f;
        const float dZf = kbdt * Zb - kfdt * Zf;
        const float dZb = kfdt * Zf - kbdt * Zb;
        const float nZf1 = fmaf(Zf, E1f, add0f) + dZf;
        const float nZb1 = fmaf(Zb, E1b, add0b) + dZb;
        Zf = nZf1; Zb = nZb1;

        {
            const float r  = Fpr * b0c - Fpi * b0s;
            const float i_ = Fpr * b0s + Fpi * b0c;
            const float r2 = Fmr * b0c + Fmi * b0s;
            const float i2 = Fmi * b0c - Fmr * b0s;
            Fpr = r; Fpi = i_; Fmr = r2; Fmi = i2;
        }

        const float half = 0.5f * fa * b1;
        const float ca = __cosf(half), sa = __sinf(half);
        const float cph = __cosf(ph), sph = __sinf(ph);
        const float ca2 = ca * ca, sa2 = sa * sa, casa = ca * sa;
        const float cd  = ca2 - sa2;
        const float e2c = cph * cph - sph * sph;
        const float e2s = 2.f * cph * sph;
        const float t1r = Fmr * e2c + Fmi * e2s;
        const float t1i = Fmr * e2s - Fmi * e2c;
        const float t2r = Fpr * e2c - Fpi * e2s;
        const float t2i = -(Fpr * e2s) - Fpi * e2c;
        const float zc = Zf * cph, zs = Zf * sph;
        const float nFpr = ca2 * Fpr + sa2 * t1r - casa * zs;
        const float nFpi = ca2 * Fpi + sa2 * t1i + casa * zc;
        const float nFmr = sa2 * t2r + ca2 * Fmr - casa * zs;
        const float nFmi = sa2 * t2i + ca2 * Fmi - casa * zc;
        const float nZf = casa * ((Fpi * cph - Fpr * sph) - (Fmi * cph + Fmr * sph)) + cd * Zf;
        Fpr = nFpr; Fpi = nFpi; Fmr = nFmr; Fmi = nFmi; Zf = nZf;

        const float sFpr = __shfl_up(Fpr, 1);
        const float sFpi = __shfl_up(Fpi, 1);
        const float sZf  = __shfl_up(Zf, 1);
        const float sZb  = __shfl_up(Zb, 1);
        const float sFmr = __shfl_down(Fmr, 1);
        const float sFmi = __shfl_down(Fmi, 1);
        const bool s0 = (s == 0), sE = (s == NSTATES - 1);
        Fpr = s0 ? 0.f : sFpr;
        Fpi = s0 ? 0.f : sFpi;
        Zf  = s0 ? 0.f : sZf;
        Zb  = s0 ? 0.f : sZb;
        Fmr = sE ? 0.f : sFmr;
        Fmi = sE ? 0.f : sFmi;

        if (valid) {
            float* dst = lds[p & 1] + lb * (NSTATES * 10) + s * 10;
            ((float2*)dst)[0] = make_float2(Fpr, Fpi);
            ((float2*)dst)[1] = make_float2(Fmr, Fmi);
            dst[4] = Zf;
            dst[9] = Zb;
        }
        __syncthreads();

        const float4* Ls = (const float4*)(lds[p & 1]);
        float4* og = (float4*)(outb + (size_t)p * pstride);
        for (int i = tid; i < n4; i += 256)
            og[i] = Ls[i];
    }
}

extern "C" void kernel_launch(void* const* d_in, const int* in_sizes, int n_in,
                              void* d_out, int out_size, void* d_ws, size_t ws_size,
                              hipStream_t stream) {
    const float* fa  = (const float*)d_in[0];
    const float* ph  = (const float*)d_in[1];
    const float* T1f = (const float*)d_in[2];
    const float* T2f = (const float*)d_in[3];
    const float* T1b = (const float*)d_in[4];
    const float* T2b = (const float*)d_in[5];
    const float* kf  = (const float*)d_in[6];
    const float* kb  = (const float*)d_in[7];
    const float* B0  = (const float*)d_in[8];
    const float* B1  = (const float*)d_in[9];
    const float* wf  = (const float*)d_in[10];
    const float* wb  = (const float*)d_in[11];
    const int*   TR  = (const int*)d_in[12];
    float* out = (float*)d_out;

    const int blocks = (BATCH + BPB - 1) / BPB;   // 683
    epg_mt_kernel<<<blocks, 256, 0, stream>>>(fa, ph, T1f, T2f, T1b, T2b,
                                              kf, kb, B0, B1, wf, wb, TR, out);

    // ---- diagnostic probes on d_ws (same size as output region) ----
    const size_t out_bytes = (size_t)NPULSES * BATCH * NSTATES * 10 * sizeof(float);
    if (ws_size >= out_bytes) {
        const long n4 = (long)(out_bytes / 16);
        const int sweeps = 6;   // 6 x 880 MB so each probe outranks harness fills
        probe_fill_const<<<4096, 256, 0, stream>>>((v4f*)d_ws, n4, sweeps);
        probe_fill_vary <<<4096, 256, 0, stream>>>((v4f*)d_ws, n4, sweeps);
    }
}

// Round 9
// 1588.577 us; speedup vs baseline: 1.0211x; 1.0211x over previous
//
#include <hip/hip_runtime.h>
#include <math.h>

#define NSTATES 21
#define NPULSES 128
#define BATCH   8192
#define BPB     12   // batch elems per block: 4 waves x 3 per wave
#define REPS    3    // P1 probe: repeat full sim so our dispatch cracks top-5

typedef float v4f __attribute__((ext_vector_type(4)));

// ---------------- P2: unthrottled replica of main kernel's store stream ----
// Same grid (683x256), same per-pulse slab addresses, same 630-float4-per-
// block clamped loop -- but register-sourced values, no LDS, no barriers,
// no compute. Distinguishes address-pattern (S1) from cadence/depth (S2).
__global__ __launch_bounds__(256) void probe_pattern(v4f* __restrict__ dst,
                                                     int sweeps) {
    const int tid = threadIdx.x;
    const long pstride4 = (long)BATCH * NSTATES * 10 / 4;   // 430080
    const long base = (long)blockIdx.x * (BPB * NSTATES * 10 / 4);  // *630
    for (int sw = 0; sw < sweeps; ++sw) {
        for (int p = 0; p < NPULSES; ++p) {
            v4f* og = dst + (long)p * pstride4 + base;
            for (int i = tid; base + i < pstride4 && i < 630; i += 256) {
                unsigned u = (unsigned)i * 2654435761u ^ (unsigned)(p * 40503)
                             ^ (unsigned)sw;
                v4f val = {__uint_as_float(u),
                           __uint_as_float(u ^ 0xAAAA5555u),
                           __uint_as_float(u + 0x9E3779B9u),
                           __uint_as_float(~u)};
                og[i] = val;
            }
        }
    }
}

// ---------------- P1: R2 main kernel, whole simulation repeated REPS x ------
// Identical output every rep (recomputed from initial state) -> deterministic,
// passes validation; dur ~3x so our own PMC row appears in top-5.
__global__ __launch_bounds__(256) void epg_mt_kernel(
    const float* __restrict__ fa_arr,
    const float* __restrict__ ph_arr,
    const float* __restrict__ T1f, const float* __restrict__ T2f,
    const float* __restrict__ T1b, const float* __restrict__ T2b,
    const float* __restrict__ kfp, const float* __restrict__ kbp,
    const float* __restrict__ B0p, const float* __restrict__ B1p,
    const float* __restrict__ wfp, const float* __restrict__ wbp,
    const int*   __restrict__ TRp,
    float* __restrict__ out)
{
    __shared__ float lds[2][BPB * NSTATES * 10];   // 2 x 2520 floats

    const int tid  = threadIdx.x;
    const int lane = tid & 63;
    const int g    = lane / 21;
    const int s    = lane - g * 21;
    const int lb   = (tid >> 6) * 3 + g;
    const int b0   = blockIdx.x * BPB;
    const int b    = b0 + lb;
    const bool valid = (g < 3) && (b < BATCH);
    const int bc   = valid ? b : 0;

    for (int i = tid; i < 2 * BPB * NSTATES * 10; i += 256)
        ((float*)lds)[i] = 0.f;

    const float tr  = (float)TRp[0];
    const float dt  = tr * 0.001f;
    const float E1f = expf(-tr / T1f[bc]);
    const float E2f = expf(-tr / T2f[bc]);
    const float E1b = expf(-tr / T1b[bc]);
    const float kfdt = kfp[bc] * dt;
    const float kbdt = kbp[bc] * dt;
    const float phi  = 6.28318530717958647692f * B0p[bc] * dt;
    const float b0c  = cosf(phi), b0s = sinf(phi);
    const float wfv  = wfp[bc], wbv = wbp[bc];
    const float add0f = (s == 0) ? (1.0f - E1f) * wfv : 0.0f;
    const float add0b = (s == 0) ? (1.0f - E1b) * wbv : 0.0f;
    const float b1   = B1p[bc];

    const int nb = (BATCH - b0 < BPB) ? (BATCH - b0) : BPB;
    const int n4 = (nb * NSTATES * 10) >> 2;
    const size_t pstride = (size_t)BATCH * NSTATES * 10;
    float* outb = out + (size_t)b0 * (NSTATES * 10);

    __syncthreads();

    for (int rep = 0; rep < REPS; ++rep) {
        float Fpr = 0.f, Fpi = 0.f, Fmr = 0.f, Fmi = 0.f;
        float Zf = (s == 0) ? wfv : 0.f;
        float Zb = (s == 0) ? wbv : 0.f;

        for (int p = 0; p < NPULSES; ++p) {
            const float fa = fa_arr[p];
            const float ph = ph_arr[p];

            Fpr *= E2f; Fpi *= E2f; Fmr *= E2f; Fmi *= E2f;
            const float dZf = kbdt * Zb - kfdt * Zf;
            const float dZb = kfdt * Zf - kbdt * Zb;
            const float nZf1 = fmaf(Zf, E1f, add0f) + dZf;
            const float nZb1 = fmaf(Zb, E1b, add0b) + dZb;
            Zf = nZf1; Zb = nZb1;

            {
                const float r  = Fpr * b0c - Fpi * b0s;
                const float i_ = Fpr * b0s + Fpi * b0c;
                const float r2 = Fmr * b0c + Fmi * b0s;
                const float i2 = Fmi * b0c - Fmr * b0s;
                Fpr = r; Fpi = i_; Fmr = r2; Fmi = i2;
            }

            const float half = 0.5f * fa * b1;
            const float ca = __cosf(half), sa = __sinf(half);
            const float cph = __cosf(ph), sph = __sinf(ph);
            const float ca2 = ca * ca, sa2 = sa * sa, casa = ca * sa;
            const float cd  = ca2 - sa2;
            const float e2c = cph * cph - sph * sph;
            const float e2s = 2.f * cph * sph;
            const float t1r = Fmr * e2c + Fmi * e2s;
            const float t1i = Fmr * e2s - Fmi * e2c;
            const float t2r = Fpr * e2c - Fpi * e2s;
            const float t2i = -(Fpr * e2s) - Fpi * e2c;
            const float zc = Zf * cph, zs = Zf * sph;
            const float nFpr = ca2 * Fpr + sa2 * t1r - casa * zs;
            const float nFpi = ca2 * Fpi + sa2 * t1i + casa * zc;
            const float nFmr = sa2 * t2r + ca2 * Fmr - casa * zs;
            const float nFmi = sa2 * t2i + ca2 * Fmi - casa * zc;
            const float nZf = casa * ((Fpi * cph - Fpr * sph) - (Fmi * cph + Fmr * sph)) + cd * Zf;
            Fpr = nFpr; Fpi = nFpi; Fmr = nFmr; Fmi = nFmi; Zf = nZf;

            const float sFpr = __shfl_up(Fpr, 1);
            const float sFpi = __shfl_up(Fpi, 1);
            const float sZf  = __shfl_up(Zf, 1);
            const float sZb  = __shfl_up(Zb, 1);
            const float sFmr = __shfl_down(Fmr, 1);
            const float sFmi = __shfl_down(Fmi, 1);
            const bool s0 = (s == 0), sE = (s == NSTATES - 1);
            Fpr = s0 ? 0.f : sFpr;
            Fpi = s0 ? 0.f : sFpi;
            Zf  = s0 ? 0.f : sZf;
            Zb  = s0 ? 0.f : sZb;
            Fmr = sE ? 0.f : sFmr;
            Fmi = sE ? 0.f : sFmi;

            if (valid) {
                float* dst = lds[p & 1] + lb * (NSTATES * 10) + s * 10;
                ((float2*)dst)[0] = make_float2(Fpr, Fpi);
                ((float2*)dst)[1] = make_float2(Fmr, Fmi);
                dst[4] = Zf;
                dst[9] = Zb;
            }
            __syncthreads();

            const float4* Ls = (const float4*)(lds[p & 1]);
            float4* og = (float4*)(outb + (size_t)p * pstride);
            for (int i = tid; i < n4; i += 256)
                og[i] = Ls[i];
        }
    }
}

extern "C" void kernel_launch(void* const* d_in, const int* in_sizes, int n_in,
                              void* d_out, int out_size, void* d_ws, size_t ws_size,
                              hipStream_t stream) {
    const float* fa  = (const float*)d_in[0];
    const float* ph  = (const float*)d_in[1];
    const float* T1f = (const float*)d_in[2];
    const float* T2f = (const float*)d_in[3];
    const float* T1b = (const float*)d_in[4];
    const float* T2b = (const float*)d_in[5];
    const float* kf  = (const float*)d_in[6];
    const float* kb  = (const float*)d_in[7];
    const float* B0  = (const float*)d_in[8];
    const float* B1  = (const float*)d_in[9];
    const float* wf  = (const float*)d_in[10];
    const float* wb  = (const float*)d_in[11];
    const int*   TR  = (const int*)d_in[12];
    float* out = (float*)d_out;

    const int blocks = (BATCH + BPB - 1) / BPB;   // 683
    epg_mt_kernel<<<blocks, 256, 0, stream>>>(fa, ph, T1f, T2f, T1b, T2b,
                                              kf, kb, B0, B1, wf, wb, TR, out);

    // P2: unthrottled replica of the main kernel's store address stream.
    const size_t out_bytes = (size_t)NPULSES * BATCH * NSTATES * 10 * sizeof(float);
    if (ws_size >= out_bytes)
        probe_pattern<<<blocks, 256, 0, stream>>>((v4f*)d_ws, 5);
}

// Round 10
// 226.981 us; speedup vs baseline: 7.1465x; 6.9987x over previous
//
#include <hip/hip_runtime.h>
#include <math.h>

#define NSTATES 21
#define NPULSES 128
#define BATCH   8192
#define EPB     4      // elems per block = waves per block (256 threads)
#define RECF    (NSTATES * 10)   // 210 floats per record
#define RECPAD  224              // padded per-wave LDS slot (floats)

// R10: max-residency streaming design.
//  - 2048 blocks x 256 threads = 8192 waves = 32 waves/CU (100% residency,
//    __launch_bounds__(256,8) caps VGPR at 64). One batch elem PER WAVE.
//  - Lanes 0-20 compute the EPG step (state s = lane); idle lanes ride along.
//  - No barriers at all: each wave stages its 840B record into a wave-private
//    LDS slot (same-wave DS ops are in-order), re-reads as float2, and issues
//    2 global_store_dwordx2 per pulse. Every resident wave issues stores
//    continuously -> aggregate write concurrency ~3x all prior rounds.
//  Rationale (R6/R8/R9 probes): streaming-store BW scales with resident
//  waves (~0.6 B/cy/wave) up to ~7.2 TB/s; all prior kernels ran <=10.7
//  storing waves/CU -> 4.4-4.6 TB/s wall regardless of pattern/structure.
__global__ __launch_bounds__(256, 8) void epg_mt_kernel(
    const float* __restrict__ fa_arr,
    const float* __restrict__ ph_arr,
    const float* __restrict__ T1f, const float* __restrict__ T2f,
    const float* __restrict__ T1b, const float* __restrict__ T2b,
    const float* __restrict__ kfp, const float* __restrict__ kbp,
    const float* __restrict__ B0p, const float* __restrict__ B1p,
    const float* __restrict__ wfp, const float* __restrict__ wbp,
    const int*   __restrict__ TRp,
    float* __restrict__ out)
{
    __shared__ float lds[EPB][RECPAD];   // 4 x 896 B, wave-private slots

    const int tid  = threadIdx.x;
    const int wv   = tid >> 6;           // wave in block = local batch elem
    const int lane = tid & 63;
    const int s    = lane;               // state index for lanes 0..20
    const bool active = (lane < NSTATES);
    const int b    = blockIdx.x * EPB + wv;      // < 8192 always (2048*4)

    float* myrec = lds[wv];
    // zero wave slot once: fields 5..8 of every state stay zero forever
    for (int i = lane; i < RECPAD; i += 64)
        myrec[i] = 0.f;

    const float tr  = (float)TRp[0];
    const float dt  = tr * 0.001f;
    const float E1f = expf(-tr / T1f[b]);
    const float E2f = expf(-tr / T2f[b]);
    const float E1b = expf(-tr / T1b[b]);
    const float kfdt = kfp[b] * dt;
    const float kbdt = kbp[b] * dt;
    const float phi  = 6.28318530717958647692f * B0p[b] * dt;
    const float b0c  = cosf(phi), b0s = sinf(phi);
    const float wfv  = wfp[b], wbv = wbp[b];
    const float add0f = (s == 0) ? (1.0f - E1f) * wfv : 0.0f;
    const float add0b = (s == 0) ? (1.0f - E1b) * wbv : 0.0f;
    const float b1   = B1p[b];

    float Fpr = 0.f, Fpi = 0.f, Fmr = 0.f, Fmi = 0.f;
    float Zf = (s == 0) ? wfv : 0.f;
    float Zb = (s == 0) ? wbv : 0.f;

    const size_t pstride2 = (size_t)BATCH * RECF / 2;      // float2 per slab
    float2* outw = (float2*)(out + (size_t)b * RECF);      // 840B*b: 8B-aligned
    const float2* myrec2 = (const float2*)myrec;
    const bool has2 = lane < (RECF / 2 - 64);              // lanes 0..40

    for (int p = 0; p < NPULSES; ++p) {
        const float fa = fa_arr[p];
        const float ph = ph_arr[p];

        // --- relax + exchange ---
        Fpr *= E2f; Fpi *= E2f; Fmr *= E2f; Fmi *= E2f;
        const float dZf = kbdt * Zb - kfdt * Zf;
        const float dZb = kfdt * Zf - kbdt * Zb;
        const float nZf1 = fmaf(Zf, E1f, add0f) + dZf;
        const float nZb1 = fmaf(Zb, E1b, add0b) + dZb;
        Zf = nZf1; Zb = nZb1;

        // --- B0 precession (free pool; bound-pool F identically zero) ---
        {
            const float r  = Fpr * b0c - Fpi * b0s;
            const float i_ = Fpr * b0s + Fpi * b0c;
            const float r2 = Fmr * b0c + Fmi * b0s;
            const float i2 = Fmi * b0c - Fmr * b0s;
            Fpr = r; Fpi = i_; Fmr = r2; Fmi = i2;
        }

        // --- RF pulse (free pool only) ---
        const float half = 0.5f * fa * b1;
        const float ca = __cosf(half), sa = __sinf(half);
        const float cph = __cosf(ph), sph = __sinf(ph);
        const float ca2 = ca * ca, sa2 = sa * sa, casa = ca * sa;
        const float cd  = ca2 - sa2;
        const float e2c = cph * cph - sph * sph;
        const float e2s = 2.f * cph * sph;
        const float t1r = Fmr * e2c + Fmi * e2s;     // conj(Fmf)*eib^2
        const float t1i = Fmr * e2s - Fmi * e2c;
        const float t2r = Fpr * e2c - Fpi * e2s;     // conj(Fpf)*conj(eib^2)
        const float t2i = -(Fpr * e2s) - Fpi * e2c;
        const float zc = Zf * cph, zs = Zf * sph;    // Zf * eib
        const float nFpr = ca2 * Fpr + sa2 * t1r - casa * zs;
        const float nFpi = ca2 * Fpi + sa2 * t1i + casa * zc;
        const float nFmr = sa2 * t2r + ca2 * Fmr - casa * zs;
        const float nFmi = sa2 * t2i + ca2 * Fmi - casa * zc;
        const float nZf = casa * ((Fpi * cph - Fpr * sph) - (Fmi * cph + Fmr * sph)) + cd * Zf;
        Fpr = nFpr; Fpi = nFpi; Fmr = nFmr; Fmi = nFmi; Zf = nZf;

        // --- EPG shift (lane +/-1; s==0 / s==20 zero-fill) ---
        const float sFpr = __shfl_up(Fpr, 1);
        const float sFpi = __shfl_up(Fpi, 1);
        const float sZf  = __shfl_up(Zf, 1);
        const float sZb  = __shfl_up(Zb, 1);
        const float sFmr = __shfl_down(Fmr, 1);
        const float sFmi = __shfl_down(Fmi, 1);
        const bool s0 = (s == 0), sE = (s == NSTATES - 1);
        Fpr = s0 ? 0.f : sFpr;
        Fpi = s0 ? 0.f : sFpi;
        Zf  = s0 ? 0.f : sZf;
        Zb  = s0 ? 0.f : sZb;
        Fmr = sE ? 0.f : sFmr;
        Fmi = sE ? 0.f : sFmi;

        // --- stage record into wave-private LDS (no barrier needed:
        //     same-wave DS ops are processed in order) ---
        if (active) {
            float* dst = myrec + s * 10;
            ((float2*)dst)[0] = make_float2(Fpr, Fpi);
            ((float2*)dst)[1] = make_float2(Fmr, Fmi);
            dst[4] = Zf;
            dst[9] = Zb;
        }

        // --- re-read as float2 and stream out (2x global_store_dwordx2) ---
        float2 v0 = myrec2[lane];
        float2 v1;
        if (has2) v1 = myrec2[lane + 64];
        float2* og = outw + (size_t)p * pstride2;
        og[lane] = v0;
        if (has2) og[lane + 64] = v1;
    }
}

extern "C" void kernel_launch(void* const* d_in, const int* in_sizes, int n_in,
                              void* d_out, int out_size, void* d_ws, size_t ws_size,
                              hipStream_t stream) {
    const float* fa  = (const float*)d_in[0];
    const float* ph  = (const float*)d_in[1];
    const float* T1f = (const float*)d_in[2];
    const float* T2f = (const float*)d_in[3];
    const float* T1b = (const float*)d_in[4];
    const float* T2b = (const float*)d_in[5];
    const float* kf  = (const float*)d_in[6];
    const float* kb  = (const float*)d_in[7];
    const float* B0  = (const float*)d_in[8];
    const float* B1  = (const float*)d_in[9];
    const float* wf  = (const float*)d_in[10];
    const float* wb  = (const float*)d_in[11];
    const int*   TR  = (const int*)d_in[12];
    float* out = (float*)d_out;

    const int blocks = BATCH / EPB;   // 2048 blocks -> 8192 waves = 32/CU
    epg_mt_kernel<<<blocks, 256, 0, stream>>>(fa, ph, T1f, T2f, T1b, T2b,
                                              kf, kb, B0, B1, wf, wb, TR, out);
}